// Round 2
// baseline (316.129 us; speedup 1.0000x reference)
//
#include <hip/hip_runtime.h>

// Sizes fixed by the reference
// B=8, NA=NB=2048, in_A=in_B=256, D=64

__device__ __forceinline__ float wave_reduce_sum(float v) {
  #pragma unroll
  for (int off = 1; off < 64; off <<= 1)
    v += __shfl_xor(v, off, 64);
  return v;
}

// Detect mask element size: flag=1 if 1-byte (bool/uint8), 0 if 4-byte (int32/fp32).
// For 4-byte little-endian 0/1 (or 0.0f/1.0f) values, bytes at i%4==1,2 are always 0
// (0x3f80.. has nonzero only in bytes 2,3; ints 0/1 only in byte 0 — check bytes 1 only
// would miss fp32; check i%4==1 which is zero for BOTH int32 0/1 and fp32 0/1).
__global__ void mask_detect_kernel(const unsigned char* __restrict__ m, int* __restrict__ flag) {
  const int t = threadIdx.x;
  unsigned v = 0;
  for (int i = t; i < 65536; i += 256)
    if ((i & 3) == 1) v |= m[i];
  __shared__ unsigned red[4];
  unsigned long long b = __ballot(v != 0);
  const int wave = t >> 6, lane = t & 63;
  if (lane == 0) red[wave] = (b != 0ull) ? 1u : 0u;
  __syncthreads();
  if (t == 0) flag[0] = (red[0] | red[1] | red[2] | red[3]) ? 1 : 0;
}

// vA[k] = sum_f WA_w[k,f]*aA_w[f]; cA = WA_b·aA_w + aA_b
__global__ void prep_kernel(const float* __restrict__ WA_w, const float* __restrict__ WA_b,
                            const float* __restrict__ aA_w, const float* __restrict__ aA_b,
                            float* __restrict__ vA, float* __restrict__ cA) {
  int t = threadIdx.x;
  float sa = 0.f;
  for (int f = 0; f < 64; ++f) sa += WA_w[t * 64 + f] * aA_w[f];
  vA[t] = sa;
  if (t == 0) {
    float ca = aA_b[0];
    for (int f = 0; f < 64; ++f) ca += WA_b[f] * aA_w[f];
    cA[0] = ca;
  }
}

// sA[row] = h_A[row,:]·vA + cA   (one wave per row, float4 loads)
__global__ __launch_bounds__(256) void sA_kernel(const float* __restrict__ hA,
                                                 const float* __restrict__ vA,
                                                 const float* __restrict__ cA,
                                                 float* __restrict__ sA) {
  const int wave = threadIdx.x >> 6, lane = threadIdx.x & 63;
  const int row = blockIdx.x * 4 + wave;  // 16384 rows total
  const float4 h4 = reinterpret_cast<const float4*>(hA + (size_t)row * 256)[lane];
  const float4 v4 = reinterpret_cast<const float4*>(vA)[lane];
  float s = h4.x * v4.x + h4.y * v4.y + h4.z * v4.z + h4.w * v4.w;
  s = wave_reduce_sum(s);
  if (lane == 0) sA[row] = s + cA[0];
}

// z_B = h_B @ WB_w + WB_b  -> zB [8*2048, 64];  sB[row] = z_B[row,:]·aB_w + aB_b
__global__ __launch_bounds__(256) void zB_kernel(const float* __restrict__ hB,
                                                 const float* __restrict__ WB_w,
                                                 const float* __restrict__ WB_b,
                                                 const float* __restrict__ aB_w,
                                                 const float* __restrict__ aB_b,
                                                 float* __restrict__ zB,
                                                 float* __restrict__ sB) {
  __shared__ float Wl[128 * 64];   // 32 KB (one k-half of WB_w)
  __shared__ float hl[16 * 256];   // 16 KB (16 rows of h_B)
  const int t = threadIdx.x;
  const int r0 = blockIdx.x * 16;
  const int wave = t >> 6, lane = t & 63;

  const float4* h4 = reinterpret_cast<const float4*>(hB + (size_t)r0 * 256);
  float4* hl4 = reinterpret_cast<float4*>(hl);
  #pragma unroll
  for (int i = 0; i < 4; ++i) hl4[t + i * 256] = h4[t + i * 256];

  float acc[4];
  const float bias = WB_b[lane];
  #pragma unroll
  for (int rr = 0; rr < 4; ++rr) acc[rr] = bias;

  const float4* W4 = reinterpret_cast<const float4*>(WB_w);
  float4* Wl4 = reinterpret_cast<float4*>(Wl);
  for (int half = 0; half < 2; ++half) {
    __syncthreads();
    #pragma unroll
    for (int i = 0; i < 8; ++i) Wl4[t + i * 256] = W4[half * 2048 + t + i * 256];
    __syncthreads();
    #pragma unroll
    for (int rr = 0; rr < 4; ++rr) {
      const int lr = wave * 4 + rr;
      #pragma unroll 8
      for (int k = 0; k < 128; ++k)
        acc[rr] = fmaf(hl[lr * 256 + half * 128 + k], Wl[k * 64 + lane], acc[rr]);
    }
  }
  const float aw = aB_w[lane], cb = aB_b[0];
  #pragma unroll
  for (int rr = 0; rr < 4; ++rr) {
    const int lr = wave * 4 + rr;
    zB[(size_t)(r0 + lr) * 64 + lane] = acc[rr];
    float s = wave_reduce_sum(acc[rr] * aw);
    if (lane == 0) sB[r0 + lr] = s + cb;
  }
}

// per-batch max over sB (for a safe softmax bound)
__global__ void maxsB_kernel(const float* __restrict__ sB, float* __restrict__ msB) {
  const int b = blockIdx.x, t = threadIdx.x;
  float m = -1e30f;
  for (int i = t; i < 2048; i += 256) m = fmaxf(m, sB[b * 2048 + i]);
  #pragma unroll
  for (int off = 1; off < 64; off <<= 1) m = fmaxf(m, __shfl_xor(m, off, 64));
  __shared__ float red[4];
  const int wave = t >> 6, lane = t & 63;
  if (lane == 0) red[wave] = m;
  __syncthreads();
  if (t == 0) msB[b] = fmaxf(fmaxf(red[0], red[1]), fmaxf(red[2], red[3]));
}

// Main fused kernel: per (batch, 32-row tile), iterate m in tiles of 64:
// w = mask ? exp(leaky(sA+sB) - M_n) : 0 ; out = (w @ zB_tile) / sum(w)
__global__ __launch_bounds__(256) void gat_kernel(
    const float* __restrict__ zB, const float* __restrict__ sA,
    const float* __restrict__ sB, const float* __restrict__ msB,
    const unsigned char* __restrict__ mask8, const int* __restrict__ mask32,
    const int* __restrict__ mflag, float* __restrict__ out) {
  const int b = blockIdx.y;
  const int n0 = blockIdx.x * 32;
  const int t = threadIdx.x, wave = t >> 6, lane = t & 63;
  const int nb = wave * 8;
  const bool use8 = (*mflag != 0);

  __shared__ float zbl[64 * 64];  // [mm][f]  16 KB
  __shared__ float wl[32 * 64];   // [n][mm]   8 KB

  // phase-1 rows handled by this thread: n_j = wave + 4j
  float sAr[8], Mr[8];
  const float mb = msB[b];
  #pragma unroll
  for (int j = 0; j < 8; ++j) {
    const float s = sA[b * 2048 + n0 + wave + 4 * j];
    sAr[j] = s;
    const float x = s + mb;
    Mr[j] = x >= 0.f ? x : 0.01f * x;   // upper bound on leaky(sA+sB[m]) (leaky monotone)
  }
  float acc[8], dacc[8];
  #pragma unroll
  for (int i = 0; i < 8; ++i) { acc[i] = 0.f; dacc[i] = 0.f; }

  const size_t mrow = ((size_t)b * 2048 + n0) * 2048;
  const float4* zB4 = reinterpret_cast<const float4*>(zB + (size_t)b * 2048 * 64);
  float4* zbl4 = reinterpret_cast<float4*>(zbl);

  for (int mt = 0; mt < 32; ++mt) {
    const int m0 = mt * 64;
    // stage zB tile [64 rows][64 f]
    #pragma unroll
    for (int i = 0; i < 4; ++i)
      zbl4[t + i * 256] = zB4[mt * 1024 + t + i * 256];
    // compute w tile [32 n][64 m]
    const float sb = sB[b * 2048 + m0 + lane];
    #pragma unroll
    for (int j = 0; j < 8; ++j) {
      const int n = wave + 4 * j;
      const size_t idx = mrow + (size_t)n * 2048 + m0 + lane;
      const bool mk = use8 ? (mask8[idx] != 0) : (mask32[idx] != 0);
      const float x = sAr[j] + sb;
      const float e = x >= 0.f ? x : 0.01f * x;
      wl[n * 64 + lane] = mk ? __expf(e - Mr[j]) : 0.f;
    }
    __syncthreads();
    // phase 2: acc[i] += wl[nb+i][mm] * zbl[mm][lane]
    #pragma unroll 4
    for (int mm = 0; mm < 64; ++mm) {
      const float z = zbl[mm * 64 + lane];
      #pragma unroll
      for (int i = 0; i < 8; ++i)
        acc[i] = fmaf(wl[(nb + i) * 64 + mm], z, acc[i]);
    }
    #pragma unroll
    for (int i = 0; i < 8; ++i) dacc[i] += wl[(nb + i) * 64 + lane];
    __syncthreads();
  }
  #pragma unroll
  for (int i = 0; i < 8; ++i) {
    const float d = wave_reduce_sum(dacc[i]);
    const float o = d > 0.f ? acc[i] / d : 0.f;
    out[((size_t)b * 2048 + n0 + nb + i) * 64 + lane] = o;
  }
}

extern "C" void kernel_launch(void* const* d_in, const int* in_sizes, int n_in,
                              void* d_out, int out_size, void* d_ws, size_t ws_size,
                              hipStream_t stream) {
  const float* h_A = (const float*)d_in[0];
  const float* h_B = (const float*)d_in[1];
  const unsigned char* mask8 = (const unsigned char*)d_in[2];
  const int* mask32 = (const int*)d_in[2];
  const float* WA_w = (const float*)d_in[3];
  const float* WA_b = (const float*)d_in[4];
  const float* WB_w = (const float*)d_in[5];
  const float* WB_b = (const float*)d_in[6];
  const float* aA_w = (const float*)d_in[7];
  const float* aA_b = (const float*)d_in[8];
  const float* aB_w = (const float*)d_in[9];
  const float* aB_b = (const float*)d_in[10];
  float* out = (float*)d_out;

  float* ws = (float*)d_ws;
  float* zB  = ws;               // 8*2048*64 = 1048576 floats (4 MB)
  float* sA  = ws + 1048576;     // 16384
  float* sB  = sA + 16384;       // 16384
  float* vA  = sB + 16384;       // 256
  float* cA  = vA + 256;         // 1
  float* msB = cA + 1;           // 8
  int* mflag = (int*)(msB + 8);  // 1

  mask_detect_kernel<<<1, 256, 0, stream>>>(mask8, mflag);
  prep_kernel<<<1, 256, 0, stream>>>(WA_w, WA_b, aA_w, aA_b, vA, cA);
  sA_kernel<<<4096, 256, 0, stream>>>(h_A, vA, cA, sA);
  zB_kernel<<<1024, 256, 0, stream>>>(h_B, WB_w, WB_b, aB_w, aB_b, zB, sB);
  maxsB_kernel<<<8, 256, 0, stream>>>(sB, msB);
  gat_kernel<<<dim3(64, 8), 256, 0, stream>>>(zB, sA, sB, msB, mask8, mask32, mflag, out);
}

// Round 3
// 140.720 us; speedup vs baseline: 2.2465x; 2.2465x over previous
//
#include <hip/hip_runtime.h>

// B=8, NA=NB=2048, in=256, D=64
typedef short bf16x8 __attribute__((ext_vector_type(8)));
typedef float f32x4 __attribute__((ext_vector_type(4)));

__device__ __forceinline__ unsigned short f2bf(float x) {
  unsigned u = __float_as_uint(x);
  u += 0x7FFFu + ((u >> 16) & 1u);
  return (unsigned short)(u >> 16);
}
__device__ __forceinline__ float bf2f(unsigned short h) {
  return __uint_as_float(((unsigned)h) << 16);
}

__device__ __forceinline__ float wave_reduce_sum(float v) {
  #pragma unroll
  for (int off = 1; off < 64; off <<= 1) v += __shfl_xor(v, off, 64);
  return v;
}

// Detect mask element size: 1 if 1-byte, 0 if 4-byte (bytes at i%4==1 are 0 for int32/fp32 0/1).
__global__ void mask_detect_kernel(const unsigned char* __restrict__ m, int* __restrict__ flag) {
  const int t = threadIdx.x;
  unsigned v = 0;
  for (int i = t; i < 65536; i += 256)
    if ((i & 3) == 1) v |= m[i];
  __shared__ unsigned red[4];
  unsigned long long b = __ballot(v != 0);
  const int wave = t >> 6, lane = t & 63;
  if (lane == 0) red[wave] = (b != 0ull) ? 1u : 0u;
  __syncthreads();
  if (t == 0) flag[0] = (red[0] | red[1] | red[2] | red[3]) ? 1 : 0;
}

// blocks 0..63: WBT[f][k] = bf16(WB_w[k][f]);  block 64: vA = WA_w@aA_w, cA
__global__ void prep_kernel(const float* __restrict__ WA_w, const float* __restrict__ WA_b,
                            const float* __restrict__ aA_w, const float* __restrict__ aA_b,
                            const float* __restrict__ WB_w,
                            float* __restrict__ vA, float* __restrict__ cA,
                            unsigned short* __restrict__ WBT) {
  if (blockIdx.x < 64) {
    const int f = blockIdx.x, k = threadIdx.x;
    WBT[f * 256 + k] = f2bf(WB_w[k * 64 + f]);
    return;
  }
  const int t = threadIdx.x;
  float sa = 0.f;
  for (int ff = 0; ff < 64; ++ff) sa += WA_w[t * 64 + ff] * aA_w[ff];
  vA[t] = sa;
  if (t == 0) {
    float ca = aA_b[0];
    for (int ff = 0; ff < 64; ++ff) ca += WA_b[ff] * aA_w[ff];
    cA[0] = ca;
  }
}

// sA[row] = h_A[row,:]·vA + cA
__global__ __launch_bounds__(256) void sA_kernel(const float* __restrict__ hA,
                                                 const float* __restrict__ vA,
                                                 const float* __restrict__ cA,
                                                 float* __restrict__ sA) {
  const int wave = threadIdx.x >> 6, lane = threadIdx.x & 63;
  const int row = blockIdx.x * 4 + wave;
  const float4 h4 = reinterpret_cast<const float4*>(hA + (size_t)row * 256)[lane];
  const float4 v4 = reinterpret_cast<const float4*>(vA)[lane];
  float s = h4.x * v4.x + h4.y * v4.y + h4.z * v4.z + h4.w * v4.w;
  s = wave_reduce_sum(s);
  if (lane == 0) sA[row] = s + cA[0];
}

// MFMA GEMM: zBT[b][f][m] = bf16(h_B @ WB_w + WB_b), sB[m] = z·aB_w + aB_b
// 64 rows/block; LDS: hl [64][256] bf16 swizzled, wt [64][256] bf16 swizzled.
__global__ __launch_bounds__(256) void zB_kernel(
    const float* __restrict__ hB, const unsigned short* __restrict__ WBT,
    const float* __restrict__ WB_b, const float* __restrict__ aB_w,
    const float* __restrict__ aB_b,
    unsigned short* __restrict__ zBT, float* __restrict__ sB) {
  __shared__ char hl[32768];
  __shared__ char wt[32768];
  const int t = threadIdx.x, w = t >> 6, l = t & 63;
  const int q = l >> 4, ln = l & 15;
  const int r0 = blockIdx.x * 64;
  const int b = r0 >> 11;
  const int mloc = r0 & 2047;

  {  // stage WBT -> wt[f][k]
    const int f = t >> 2, c = t & 3;
    const unsigned short* src = WBT + f * 256;
    #pragma unroll
    for (int j = 0; j < 8; ++j) {
      const int k8 = c + j * 4;
      bf16x8 v = *(const bf16x8*)(src + k8 * 8);
      *(bf16x8*)(wt + ((f * 512 + k8 * 16) ^ ((f & 7) << 4))) = v;
    }
  }
  {  // stage h_B -> hl[row][k] (fp32 -> bf16)
    const int row = t >> 2, seg = t & 3;
    const float* src = hB + (size_t)(r0 + row) * 256 + seg * 64;
    #pragma unroll
    for (int i = 0; i < 8; ++i) {
      float4 x = *(const float4*)(src + i * 8);
      float4 y = *(const float4*)(src + i * 8 + 4);
      bf16x8 v;
      v[0] = (short)f2bf(x.x); v[1] = (short)f2bf(x.y);
      v[2] = (short)f2bf(x.z); v[3] = (short)f2bf(x.w);
      v[4] = (short)f2bf(y.x); v[5] = (short)f2bf(y.y);
      v[6] = (short)f2bf(y.z); v[7] = (short)f2bf(y.w);
      *(bf16x8*)(hl + ((row * 512 + seg * 128 + i * 16) ^ ((row & 7) << 4))) = v;
    }
  }
  __syncthreads();
  f32x4 acc[4];
  #pragma unroll
  for (int nr = 0; nr < 4; ++nr) acc[nr] = (f32x4){0.f, 0.f, 0.f, 0.f};
  const int rowA = w * 16 + ln;
  #pragma unroll
  for (int kk = 0; kk < 8; ++kk) {
    const int ko = kk * 64 + q * 16;
    bf16x8 a = *(const bf16x8*)(hl + ((rowA * 512 + ko) ^ ((rowA & 7) << 4)));
    #pragma unroll
    for (int nr = 0; nr < 4; ++nr) {
      const int f = nr * 16 + ln;
      bf16x8 bb = *(const bf16x8*)(wt + ((f * 512 + ko) ^ ((f & 7) << 4)));
      acc[nr] = __builtin_amdgcn_mfma_f32_16x16x32_bf16(a, bb, acc[nr], 0, 0, 0);
    }
  }
  // epilogue: bias, sB, transpose-store via LDS
  float z[4][4];
  float p[4] = {0.f, 0.f, 0.f, 0.f};
  #pragma unroll
  for (int nr = 0; nr < 4; ++nr) {
    const int f = nr * 16 + ln;
    const float bias = WB_b[f];
    const float aw = aB_w[f];
    #pragma unroll
    for (int r = 0; r < 4; ++r) {
      const float zz = acc[nr][r] + bias;
      z[nr][r] = zz;
      p[r] += zz * aw;
    }
  }
  #pragma unroll
  for (int r = 0; r < 4; ++r) {
    #pragma unroll
    for (int off = 1; off < 16; off <<= 1) p[r] += __shfl_xor(p[r], off, 16);
  }
  if (ln == 0) {
    const float cb = aB_b[0];
    #pragma unroll
    for (int r = 0; r < 4; ++r) sB[r0 + w * 16 + q * 4 + r] = p[r] + cb;
  }
  __syncthreads();  // hl reused as zt[f][m] bf16
  #pragma unroll
  for (int nr = 0; nr < 4; ++nr) {
    const int f = nr * 16 + ln;
    uint2 pk;
    pk.x = (unsigned)f2bf(z[nr][0]) | ((unsigned)f2bf(z[nr][1]) << 16);
    pk.y = (unsigned)f2bf(z[nr][2]) | ((unsigned)f2bf(z[nr][3]) << 16);
    *(uint2*)(hl + ((f * 128 + (w * 16 + q * 4) * 2) ^ ((f & 7) << 4))) = pk;
  }
  __syncthreads();
  {
    const int sf = t >> 3, sm8 = t & 7;
    #pragma unroll
    for (int i = 0; i < 2; ++i) {
      const int f = sf + i * 32;
      bf16x8 v = *(const bf16x8*)(hl + ((f * 128 + sm8 * 16) ^ ((f & 7) << 4)));
      *(bf16x8*)(zBT + (size_t)b * 131072 + f * 2048 + mloc + sm8 * 8) = v;
    }
  }
}

__global__ void maxsB_kernel(const float* __restrict__ sB, float* __restrict__ msB) {
  const int b = blockIdx.x, t = threadIdx.x;
  float m = -1e30f;
  for (int i = t; i < 2048; i += 256) m = fmaxf(m, sB[b * 2048 + i]);
  #pragma unroll
  for (int off = 1; off < 64; off <<= 1) m = fmaxf(m, __shfl_xor(m, off, 64));
  __shared__ float red[4];
  const int wave = t >> 6, lane = t & 63;
  if (lane == 0) red[wave] = m;
  __syncthreads();
  if (t == 0) msB[b] = fmaxf(fmaxf(red[0], red[1]), fmaxf(red[2], red[3]));
}

// Fused GAT: per (batch, 32-n tile), K-loop over m in tiles of 64.
// w bf16 -> swizzled LDS [32n][64m]; zBT tile -> swizzled LDS [64f][64m];
// PV via mfma_f32_16x16x32_bf16; denom accumulated in registers.
__global__ __launch_bounds__(256) void gat_kernel(
    const unsigned short* __restrict__ zBT, const float* __restrict__ sA,
    const float* __restrict__ sB, const float* __restrict__ msB,
    const unsigned char* __restrict__ mask8, const int* __restrict__ mask32,
    const int* __restrict__ mflag, float* __restrict__ out) {
  const int b = blockIdx.y;
  const int n0 = blockIdx.x * 32;
  const int t = threadIdx.x;
  const int w = t >> 6, l = t & 63;
  const int q = l >> 4, ln = l & 15;
  const bool use8 = (*mflag != 0);

  __shared__ char zbl[8192];  // [64f][64m] bf16 swizzled
  __shared__ char wl[4096];   // [32n][64m] bf16 swizzled
  __shared__ float dl[32];

  const int n2 = t >> 4;   // row pair: n2, n2+16
  const int m4 = t & 15;   // 4 m's per thread
  const float mb = msB[b];
  const float sA0 = sA[b * 2048 + n0 + n2];
  const float sA1 = sA[b * 2048 + n0 + 16 + n2];
  const float M0f = sA0 + mb, M1f = sA1 + mb;
  const float M0 = M0f >= 0.f ? M0f : 0.01f * M0f;
  const float M1 = M1f >= 0.f ? M1f : 0.01f * M1f;
  float ds0 = 0.f, ds1 = 0.f;

  f32x4 acc0 = (f32x4){0.f, 0.f, 0.f, 0.f}, acc1 = acc0;

  const unsigned short* zb = zBT + (size_t)b * 131072;
  const size_t mrow0 = ((size_t)(b * 2048 + n0 + n2)) * 2048 + m4 * 4;
  const size_t mrow1 = mrow0 + (size_t)16 * 2048;
  const int sf = t >> 3, sm8 = t & 7;
  const int wbyte0 = (n2 * 128 + m4 * 8) ^ ((n2 & 7) << 4);
  const int wbyte1 = ((n2 + 16) * 128 + m4 * 8) ^ (((n2 + 16) & 7) << 4);
  const int fB = w * 16 + ln;

  for (int mt = 0; mt < 32; ++mt) {
    const int m0 = mt * 64;
    #pragma unroll
    for (int i = 0; i < 2; ++i) {  // stage zbl
      const int f = sf + i * 32;
      bf16x8 v = *(const bf16x8*)(zb + f * 2048 + m0 + sm8 * 8);
      *(bf16x8*)(zbl + ((f * 128 + sm8 * 16) ^ ((f & 7) << 4))) = v;
    }
    const float4 sb4 = *(const float4*)(sB + b * 2048 + m0 + m4 * 4);
    const float sbx[4] = {sb4.x, sb4.y, sb4.z, sb4.w};
    int k0[4], k1[4];
    if (use8) {
      uchar4 a = *(const uchar4*)(mask8 + mrow0 + m0);
      uchar4 c = *(const uchar4*)(mask8 + mrow1 + m0);
      k0[0] = a.x; k0[1] = a.y; k0[2] = a.z; k0[3] = a.w;
      k1[0] = c.x; k1[1] = c.y; k1[2] = c.z; k1[3] = c.w;
    } else {
      int4 a = *(const int4*)(mask32 + mrow0 + m0);
      int4 c = *(const int4*)(mask32 + mrow1 + m0);
      k0[0] = a.x; k0[1] = a.y; k0[2] = a.z; k0[3] = a.w;
      k1[0] = c.x; k1[1] = c.y; k1[2] = c.z; k1[3] = c.w;
    }
    unsigned short wb0[4], wb1[4];
    #pragma unroll
    for (int j = 0; j < 4; ++j) {
      const float x0 = sA0 + sbx[j];
      const float e0 = x0 >= 0.f ? x0 : 0.01f * x0;
      const float v0 = k0[j] ? __expf(e0 - M0) : 0.f;
      wb0[j] = f2bf(v0); ds0 += bf2f(wb0[j]);
      const float x1 = sA1 + sbx[j];
      const float e1 = x1 >= 0.f ? x1 : 0.01f * x1;
      const float v1 = k1[j] ? __expf(e1 - M1) : 0.f;
      wb1[j] = f2bf(v1); ds1 += bf2f(wb1[j]);
    }
    uint2 p0, p1;
    p0.x = (unsigned)wb0[0] | ((unsigned)wb0[1] << 16);
    p0.y = (unsigned)wb0[2] | ((unsigned)wb0[3] << 16);
    p1.x = (unsigned)wb1[0] | ((unsigned)wb1[1] << 16);
    p1.y = (unsigned)wb1[2] | ((unsigned)wb1[3] << 16);
    *(uint2*)(wl + wbyte0) = p0;
    *(uint2*)(wl + wbyte1) = p1;
    __syncthreads();
    #pragma unroll
    for (int kk = 0; kk < 2; ++kk) {
      const int ko = kk * 64 + q * 16;
      bf16x8 bb = *(const bf16x8*)(zbl + ((fB * 128 + ko) ^ ((fB & 7) << 4)));
      bf16x8 a0 = *(const bf16x8*)(wl + ((ln * 128 + ko) ^ ((ln & 7) << 4)));
      bf16x8 a1 = *(const bf16x8*)(wl + (((16 + ln) * 128 + ko) ^ (((16 + ln) & 7) << 4)));
      acc0 = __builtin_amdgcn_mfma_f32_16x16x32_bf16(a0, bb, acc0, 0, 0, 0);
      acc1 = __builtin_amdgcn_mfma_f32_16x16x32_bf16(a1, bb, acc1, 0, 0, 0);
    }
    __syncthreads();
  }
  #pragma unroll
  for (int off = 1; off < 16; off <<= 1) {
    ds0 += __shfl_xor(ds0, off, 16);
    ds1 += __shfl_xor(ds1, off, 16);
  }
  if (m4 == 0) { dl[n2] = ds0; dl[n2 + 16] = ds1; }
  __syncthreads();
  #pragma unroll
  for (int r = 0; r < 4; ++r) {
    {
      const int n = q * 4 + r;
      const float d = dl[n];
      out[((size_t)(b * 2048 + n0 + n)) * 64 + w * 16 + ln] = d > 0.f ? acc0[r] / d : 0.f;
    }
    {
      const int n = 16 + q * 4 + r;
      const float d = dl[n];
      out[((size_t)(b * 2048 + n0 + n)) * 64 + w * 16 + ln] = d > 0.f ? acc1[r] / d : 0.f;
    }
  }
}

extern "C" void kernel_launch(void* const* d_in, const int* in_sizes, int n_in,
                              void* d_out, int out_size, void* d_ws, size_t ws_size,
                              hipStream_t stream) {
  const float* h_A = (const float*)d_in[0];
  const float* h_B = (const float*)d_in[1];
  const unsigned char* mask8 = (const unsigned char*)d_in[2];
  const int* mask32 = (const int*)d_in[2];
  const float* WA_w = (const float*)d_in[3];
  const float* WA_b = (const float*)d_in[4];
  const float* WB_w = (const float*)d_in[5];
  const float* WB_b = (const float*)d_in[6];
  const float* aA_w = (const float*)d_in[7];
  const float* aA_b = (const float*)d_in[8];
  const float* aB_w = (const float*)d_in[9];
  const float* aB_b = (const float*)d_in[10];
  float* out = (float*)d_out;

  // ws layout (bytes): zBT 0..2MB, WBT +32KB, then fp32 arrays
  char* wsb = (char*)d_ws;
  unsigned short* zBT = (unsigned short*)wsb;              // 2,097,152 B
  unsigned short* WBT = (unsigned short*)(wsb + 2097152);  // 32,768 B
  float* sA  = (float*)(wsb + 2129920);                    // 65,536 B
  float* sB  = (float*)(wsb + 2195456);                    // 65,536 B
  float* vA  = (float*)(wsb + 2260992);                    // 1,024 B
  float* cA  = (float*)(wsb + 2262016);                    // 4 B
  float* msB = (float*)(wsb + 2262020);                    // 32 B
  int* mflag = (int*)(wsb + 2262052);                      // 4 B

  mask_detect_kernel<<<1, 256, 0, stream>>>(mask8, mflag);
  prep_kernel<<<65, 256, 0, stream>>>(WA_w, WA_b, aA_w, aA_b, WB_w, vA, cA, WBT);
  sA_kernel<<<4096, 256, 0, stream>>>(h_A, vA, cA, sA);
  zB_kernel<<<256, 256, 0, stream>>>(h_B, WBT, WB_b, aB_w, aB_b, zBT, sB);
  maxsB_kernel<<<8, 256, 0, stream>>>(sB, msB);
  gat_kernel<<<dim3(64, 8), 256, 0, stream>>>(zBT, sA, sB, msB, mask8, mask32, mflag, out);
}

// Round 4
// 81.069 us; speedup vs baseline: 3.8995x; 1.7358x over previous
//
#include <hip/hip_runtime.h>

// B=8, NA=NB=2048, in=256, D=64
typedef short bf16x8 __attribute__((ext_vector_type(8)));
typedef float f32x4 __attribute__((ext_vector_type(4)));

__device__ __forceinline__ unsigned short f2bf(float x) {
  unsigned u = __float_as_uint(x);
  u += 0x7FFFu + ((u >> 16) & 1u);
  return (unsigned short)(u >> 16);
}
__device__ __forceinline__ float bf2f(unsigned short h) {
  return __uint_as_float(((unsigned)h) << 16);
}

__device__ __forceinline__ float wave_reduce_sum(float v) {
  #pragma unroll
  for (int off = 1; off < 64; off <<= 1) v += __shfl_xor(v, off, 64);
  return v;
}

// Detect mask element size: 1 if 1-byte, 0 if 4-byte.
// For 4-byte 0/1 (int32 or fp32), byte at i%4==1 is always 0; for random bool
// bytes, 256 samples all-zero has P=2^-256. One load per thread.
__global__ void mask_detect_kernel(const unsigned char* __restrict__ m, int* __restrict__ flag) {
  const int t = threadIdx.x;
  const unsigned v = m[t * 4 + 1];
  unsigned long long b = __ballot(v != 0);
  __shared__ unsigned red[4];
  const int wave = t >> 6, lane = t & 63;
  if (lane == 0) red[wave] = (b != 0ull) ? 1u : 0u;
  __syncthreads();
  if (t == 0) flag[0] = (red[0] | red[1] | red[2] | red[3]) ? 1 : 0;
}

// blocks 0..63: WBT[f][k] = bf16(WB_w[k][f]);  block 64: vA = WA_w@aA_w, cA
__global__ void prep_kernel(const float* __restrict__ WA_w, const float* __restrict__ WA_b,
                            const float* __restrict__ aA_w, const float* __restrict__ aA_b,
                            const float* __restrict__ WB_w,
                            float* __restrict__ vA, float* __restrict__ cA,
                            unsigned short* __restrict__ WBT) {
  if (blockIdx.x < 64) {
    const int f = blockIdx.x, k = threadIdx.x;
    WBT[f * 256 + k] = f2bf(WB_w[k * 64 + f]);
    return;
  }
  const int t = threadIdx.x;
  float sa = 0.f;
  for (int ff = 0; ff < 64; ++ff) sa += WA_w[t * 64 + ff] * aA_w[ff];
  vA[t] = sa;
  if (t == 0) {
    float ca = aA_b[0];
    for (int ff = 0; ff < 64; ++ff) ca += WA_b[ff] * aA_w[ff];
    cA[0] = ca;
  }
}

// sA[row] = h_A[row,:]·vA + cA
__global__ __launch_bounds__(256) void sA_kernel(const float* __restrict__ hA,
                                                 const float* __restrict__ vA,
                                                 const float* __restrict__ cA,
                                                 float* __restrict__ sA) {
  const int wave = threadIdx.x >> 6, lane = threadIdx.x & 63;
  const int row = blockIdx.x * 4 + wave;
  const float4 h4 = reinterpret_cast<const float4*>(hA + (size_t)row * 256)[lane];
  const float4 v4 = reinterpret_cast<const float4*>(vA)[lane];
  float s = h4.x * v4.x + h4.y * v4.y + h4.z * v4.z + h4.w * v4.w;
  s = wave_reduce_sum(s);
  if (lane == 0) sA[row] = s + cA[0];
}

// MFMA GEMM: zBT[b][f][m] = bf16(h_B @ WB_w + WB_b), sB[m] = z·aB_w + aB_b
__global__ __launch_bounds__(256) void zB_kernel(
    const float* __restrict__ hB, const unsigned short* __restrict__ WBT,
    const float* __restrict__ WB_b, const float* __restrict__ aB_w,
    const float* __restrict__ aB_b,
    unsigned short* __restrict__ zBT, float* __restrict__ sB) {
  __shared__ char hl[32768];
  __shared__ char wt[32768];
  const int t = threadIdx.x, w = t >> 6, l = t & 63;
  const int q = l >> 4, ln = l & 15;
  const int r0 = blockIdx.x * 64;
  const int b = r0 >> 11;
  const int mloc = r0 & 2047;

  {  // stage WBT -> wt[f][k]
    const int f = t >> 2, c = t & 3;
    const unsigned short* src = WBT + f * 256;
    #pragma unroll
    for (int j = 0; j < 8; ++j) {
      const int k8 = c + j * 4;
      bf16x8 v = *(const bf16x8*)(src + k8 * 8);
      *(bf16x8*)(wt + ((f * 512 + k8 * 16) ^ ((f & 7) << 4))) = v;
    }
  }
  {  // stage h_B -> hl[row][k] (fp32 -> bf16)
    const int row = t >> 2, seg = t & 3;
    const float* src = hB + (size_t)(r0 + row) * 256 + seg * 64;
    #pragma unroll
    for (int i = 0; i < 8; ++i) {
      float4 x = *(const float4*)(src + i * 8);
      float4 y = *(const float4*)(src + i * 8 + 4);
      bf16x8 v;
      v[0] = (short)f2bf(x.x); v[1] = (short)f2bf(x.y);
      v[2] = (short)f2bf(x.z); v[3] = (short)f2bf(x.w);
      v[4] = (short)f2bf(y.x); v[5] = (short)f2bf(y.y);
      v[6] = (short)f2bf(y.z); v[7] = (short)f2bf(y.w);
      *(bf16x8*)(hl + ((row * 512 + seg * 128 + i * 16) ^ ((row & 7) << 4))) = v;
    }
  }
  __syncthreads();
  f32x4 acc[4];
  #pragma unroll
  for (int nr = 0; nr < 4; ++nr) acc[nr] = (f32x4){0.f, 0.f, 0.f, 0.f};
  const int rowA = w * 16 + ln;
  #pragma unroll
  for (int kk = 0; kk < 8; ++kk) {
    const int ko = kk * 64 + q * 16;
    bf16x8 a = *(const bf16x8*)(hl + ((rowA * 512 + ko) ^ ((rowA & 7) << 4)));
    #pragma unroll
    for (int nr = 0; nr < 4; ++nr) {
      const int f = nr * 16 + ln;
      bf16x8 bb = *(const bf16x8*)(wt + ((f * 512 + ko) ^ ((f & 7) << 4)));
      acc[nr] = __builtin_amdgcn_mfma_f32_16x16x32_bf16(a, bb, acc[nr], 0, 0, 0);
    }
  }
  // epilogue: bias, sB, transpose-store via LDS
  float z[4][4];
  float p[4] = {0.f, 0.f, 0.f, 0.f};
  #pragma unroll
  for (int nr = 0; nr < 4; ++nr) {
    const int f = nr * 16 + ln;
    const float bias = WB_b[f];
    const float aw = aB_w[f];
    #pragma unroll
    for (int r = 0; r < 4; ++r) {
      const float zz = acc[nr][r] + bias;
      z[nr][r] = zz;
      p[r] += zz * aw;
    }
  }
  #pragma unroll
  for (int r = 0; r < 4; ++r) {
    #pragma unroll
    for (int off = 1; off < 16; off <<= 1) p[r] += __shfl_xor(p[r], off, 16);
  }
  if (ln == 0) {
    const float cb = aB_b[0];
    #pragma unroll
    for (int r = 0; r < 4; ++r) sB[r0 + w * 16 + q * 4 + r] = p[r] + cb;
  }
  __syncthreads();  // hl reused as zt[f][m] bf16
  #pragma unroll
  for (int nr = 0; nr < 4; ++nr) {
    const int f = nr * 16 + ln;
    uint2 pk;
    pk.x = (unsigned)f2bf(z[nr][0]) | ((unsigned)f2bf(z[nr][1]) << 16);
    pk.y = (unsigned)f2bf(z[nr][2]) | ((unsigned)f2bf(z[nr][3]) << 16);
    *(uint2*)(hl + ((f * 128 + (w * 16 + q * 4) * 2) ^ ((f & 7) << 4))) = pk;
  }
  __syncthreads();
  {
    const int sf = t >> 3, sm8 = t & 7;
    #pragma unroll
    for (int i = 0; i < 2; ++i) {
      const int f = sf + i * 32;
      bf16x8 v = *(const bf16x8*)(hl + ((f * 128 + sm8 * 16) ^ ((f & 7) << 4)));
      *(bf16x8*)(zBT + (size_t)b * 131072 + f * 2048 + mloc + sm8 * 8) = v;
    }
  }
}

__global__ void maxsB_kernel(const float* __restrict__ sB, float* __restrict__ msB) {
  const int b = blockIdx.x, t = threadIdx.x;
  float m = -1e30f;
  for (int i = t; i < 2048; i += 256) m = fmaxf(m, sB[b * 2048 + i]);
  #pragma unroll
  for (int off = 1; off < 64; off <<= 1) m = fmaxf(m, __shfl_xor(m, off, 64));
  __shared__ float red[4];
  const int wave = t >> 6, lane = t & 63;
  if (lane == 0) red[wave] = m;
  __syncthreads();
  if (t == 0) msB[b] = fmaxf(fmaxf(red[0], red[1]), fmaxf(red[2], red[3]));
}

// Fused GAT: per (batch, 32-n tile), K-loop over m in tiles of 64.
__global__ __launch_bounds__(256) void gat_kernel(
    const unsigned short* __restrict__ zBT, const float* __restrict__ sA,
    const float* __restrict__ sB, const float* __restrict__ msB,
    const unsigned char* __restrict__ mask8, const int* __restrict__ mask32,
    const int* __restrict__ mflag, float* __restrict__ out) {
  const int b = blockIdx.y;
  const int n0 = blockIdx.x * 32;
  const int t = threadIdx.x;
  const int w = t >> 6, l = t & 63;
  const int q = l >> 4, ln = l & 15;
  const bool use8 = (*mflag != 0);

  __shared__ char zbl[8192];  // [64f][64m] bf16 swizzled
  __shared__ char wl[4096];   // [32n][64m] bf16 swizzled
  __shared__ float dl[32];

  const int n2 = t >> 4;   // row pair: n2, n2+16
  const int m4 = t & 15;   // 4 m's per thread
  const float mb = msB[b];
  const float sA0 = sA[b * 2048 + n0 + n2];
  const float sA1 = sA[b * 2048 + n0 + 16 + n2];
  const float M0f = sA0 + mb, M1f = sA1 + mb;
  const float M0 = M0f >= 0.f ? M0f : 0.01f * M0f;
  const float M1 = M1f >= 0.f ? M1f : 0.01f * M1f;
  float ds0 = 0.f, ds1 = 0.f;

  f32x4 acc0 = (f32x4){0.f, 0.f, 0.f, 0.f}, acc1 = acc0;

  const unsigned short* zb = zBT + (size_t)b * 131072;
  const size_t mrow0 = ((size_t)(b * 2048 + n0 + n2)) * 2048 + m4 * 4;
  const size_t mrow1 = mrow0 + (size_t)16 * 2048;
  const int sf = t >> 3, sm8 = t & 7;
  const int wbyte0 = (n2 * 128 + m4 * 8) ^ ((n2 & 7) << 4);
  const int wbyte1 = ((n2 + 16) * 128 + m4 * 8) ^ (((n2 + 16) & 7) << 4);
  const int fB = w * 16 + ln;

  for (int mt = 0; mt < 32; ++mt) {
    const int m0 = mt * 64;
    #pragma unroll
    for (int i = 0; i < 2; ++i) {  // stage zbl
      const int f = sf + i * 32;
      bf16x8 v = *(const bf16x8*)(zb + f * 2048 + m0 + sm8 * 8);
      *(bf16x8*)(zbl + ((f * 128 + sm8 * 16) ^ ((f & 7) << 4))) = v;
    }
    const float4 sb4 = *(const float4*)(sB + b * 2048 + m0 + m4 * 4);
    const float sbx[4] = {sb4.x, sb4.y, sb4.z, sb4.w};
    int k0[4], k1[4];
    if (use8) {
      uchar4 a = *(const uchar4*)(mask8 + mrow0 + m0);
      uchar4 c = *(const uchar4*)(mask8 + mrow1 + m0);
      k0[0] = a.x; k0[1] = a.y; k0[2] = a.z; k0[3] = a.w;
      k1[0] = c.x; k1[1] = c.y; k1[2] = c.z; k1[3] = c.w;
    } else {
      int4 a = *(const int4*)(mask32 + mrow0 + m0);
      int4 c = *(const int4*)(mask32 + mrow1 + m0);
      k0[0] = a.x; k0[1] = a.y; k0[2] = a.z; k0[3] = a.w;
      k1[0] = c.x; k1[1] = c.y; k1[2] = c.z; k1[3] = c.w;
    }
    unsigned short wb0[4], wb1[4];
    #pragma unroll
    for (int j = 0; j < 4; ++j) {
      const float x0 = sA0 + sbx[j];
      const float e0 = x0 >= 0.f ? x0 : 0.01f * x0;
      const float v0 = k0[j] ? __expf(e0 - M0) : 0.f;
      wb0[j] = f2bf(v0); ds0 += bf2f(wb0[j]);
      const float x1 = sA1 + sbx[j];
      const float e1 = x1 >= 0.f ? x1 : 0.01f * x1;
      const float v1 = k1[j] ? __expf(e1 - M1) : 0.f;
      wb1[j] = f2bf(v1); ds1 += bf2f(wb1[j]);
    }
    uint2 p0, p1;
    p0.x = (unsigned)wb0[0] | ((unsigned)wb0[1] << 16);
    p0.y = (unsigned)wb0[2] | ((unsigned)wb0[3] << 16);
    p1.x = (unsigned)wb1[0] | ((unsigned)wb1[1] << 16);
    p1.y = (unsigned)wb1[2] | ((unsigned)wb1[3] << 16);
    *(uint2*)(wl + wbyte0) = p0;
    *(uint2*)(wl + wbyte1) = p1;
    __syncthreads();
    #pragma unroll
    for (int kk = 0; kk < 2; ++kk) {
      const int ko = kk * 64 + q * 16;
      bf16x8 bb = *(const bf16x8*)(zbl + ((fB * 128 + ko) ^ ((fB & 7) << 4)));
      bf16x8 a0 = *(const bf16x8*)(wl + ((ln * 128 + ko) ^ ((ln & 7) << 4)));
      bf16x8 a1 = *(const bf16x8*)(wl + (((16 + ln) * 128 + ko) ^ (((16 + ln) & 7) << 4)));
      acc0 = __builtin_amdgcn_mfma_f32_16x16x32_bf16(a0, bb, acc0, 0, 0, 0);
      acc1 = __builtin_amdgcn_mfma_f32_16x16x32_bf16(a1, bb, acc1, 0, 0, 0);
    }
    __syncthreads();
  }
  #pragma unroll
  for (int off = 1; off < 16; off <<= 1) {
    ds0 += __shfl_xor(ds0, off, 16);
    ds1 += __shfl_xor(ds1, off, 16);
  }
  if (m4 == 0) { dl[n2] = ds0; dl[n2 + 16] = ds1; }
  __syncthreads();
  #pragma unroll
  for (int r = 0; r < 4; ++r) {
    {
      const int n = q * 4 + r;
      const float d = dl[n];
      out[((size_t)(b * 2048 + n0 + n)) * 64 + w * 16 + ln] = d > 0.f ? acc0[r] / d : 0.f;
    }
    {
      const int n = 16 + q * 4 + r;
      const float d = dl[n];
      out[((size_t)(b * 2048 + n0 + n)) * 64 + w * 16 + ln] = d > 0.f ? acc1[r] / d : 0.f;
    }
  }
}

extern "C" void kernel_launch(void* const* d_in, const int* in_sizes, int n_in,
                              void* d_out, int out_size, void* d_ws, size_t ws_size,
                              hipStream_t stream) {
  const float* h_A = (const float*)d_in[0];
  const float* h_B = (const float*)d_in[1];
  const unsigned char* mask8 = (const unsigned char*)d_in[2];
  const int* mask32 = (const int*)d_in[2];
  const float* WA_w = (const float*)d_in[3];
  const float* WA_b = (const float*)d_in[4];
  const float* WB_w = (const float*)d_in[5];
  const float* WB_b = (const float*)d_in[6];
  const float* aA_w = (const float*)d_in[7];
  const float* aA_b = (const float*)d_in[8];
  const float* aB_w = (const float*)d_in[9];
  const float* aB_b = (const float*)d_in[10];
  float* out = (float*)d_out;

  // ws layout (bytes): zBT 0..2MB, WBT +32KB, then fp32 arrays
  char* wsb = (char*)d_ws;
  unsigned short* zBT = (unsigned short*)wsb;              // 2,097,152 B
  unsigned short* WBT = (unsigned short*)(wsb + 2097152);  // 32,768 B
  float* sA  = (float*)(wsb + 2129920);                    // 65,536 B
  float* sB  = (float*)(wsb + 2195456);                    // 65,536 B
  float* vA  = (float*)(wsb + 2260992);                    // 1,024 B
  float* cA  = (float*)(wsb + 2262016);                    // 4 B
  float* msB = (float*)(wsb + 2262020);                    // 32 B
  int* mflag = (int*)(wsb + 2262052);                      // 4 B

  mask_detect_kernel<<<1, 256, 0, stream>>>(mask8, mflag);
  prep_kernel<<<65, 256, 0, stream>>>(WA_w, WA_b, aA_w, aA_b, WB_w, vA, cA, WBT);
  sA_kernel<<<4096, 256, 0, stream>>>(h_A, vA, cA, sA);
  zB_kernel<<<256, 256, 0, stream>>>(h_B, WBT, WB_b, aB_w, aB_b, zBT, sB);
  maxsB_kernel<<<8, 256, 0, stream>>>(sB, msB);
  gat_kernel<<<dim3(64, 8), 256, 0, stream>>>(zBT, sA, sB, msB, mask8, mask32, mflag, out);
}

// Round 5
// 63.953 us; speedup vs baseline: 4.9431x; 1.2676x over previous
//
#include <hip/hip_runtime.h>

// B=8, NA=NB=2048, in=256, D=64
typedef short bf16x8 __attribute__((ext_vector_type(8)));
typedef float f32x4 __attribute__((ext_vector_type(4)));

__device__ __forceinline__ unsigned short f2bf(float x) {
  unsigned u = __float_as_uint(x);
  u += 0x7FFFu + ((u >> 16) & 1u);
  return (unsigned short)(u >> 16);
}
__device__ __forceinline__ float bf2f(unsigned short h) {
  return __uint_as_float(((unsigned)h) << 16);
}

__device__ __forceinline__ float wave_reduce_sum(float v) {
  #pragma unroll
  for (int off = 1; off < 64; off <<= 1) v += __shfl_xor(v, off, 64);
  return v;
}

// blocks 0..63: WBT[f][k] = bf16(WB_w[k][f])
// block 64: vA = WA_w@aA_w, cA; mask-detect -> mflag
__global__ void prep_kernel(const float* __restrict__ WA_w, const float* __restrict__ WA_b,
                            const float* __restrict__ aA_w, const float* __restrict__ aA_b,
                            const float* __restrict__ WB_w,
                            const unsigned char* __restrict__ mask8,
                            float* __restrict__ vA, float* __restrict__ cA,
                            unsigned short* __restrict__ WBT, int* __restrict__ mflag) {
  if (blockIdx.x < 64) {
    const int f = blockIdx.x, k = threadIdx.x;
    WBT[f * 256 + k] = f2bf(WB_w[k * 64 + f]);
    return;
  }
  const int t = threadIdx.x;
  // mask dtype detect: byte at i%4==1 is always 0 for int32/fp32 0/1 values;
  // 256 random bool bytes all-zero has P = 2^-256.
  const unsigned v = mask8[t * 4 + 1];
  const unsigned long long bal = __ballot(v != 0);
  __shared__ unsigned red[4];
  const int wave = t >> 6, lane = t & 63;
  if (lane == 0) red[wave] = (bal != 0ull) ? 1u : 0u;
  float sa = 0.f;
  for (int ff = 0; ff < 64; ++ff) sa += WA_w[t * 64 + ff] * aA_w[ff];
  vA[t] = sa;
  __syncthreads();
  if (t == 0) {
    float ca = aA_b[0];
    for (int ff = 0; ff < 64; ++ff) ca += WA_b[ff] * aA_w[ff];
    cA[0] = ca;
    mflag[0] = (red[0] | red[1] | red[2] | red[3]) ? 1 : 0;
  }
}

// MFMA GEMM: zBT[b][f][m] = bf16(h_B @ WB_w + WB_b); sB[m]; msB_blk[block] = max sB
__global__ __launch_bounds__(256) void zB_kernel(
    const float* __restrict__ hB, const unsigned short* __restrict__ WBT,
    const float* __restrict__ WB_b, const float* __restrict__ aB_w,
    const float* __restrict__ aB_b,
    unsigned short* __restrict__ zBT, float* __restrict__ sB,
    float* __restrict__ msB_blk) {
  __shared__ char hl[32768];
  __shared__ char wt[32768];
  __shared__ float red16[16];
  const int t = threadIdx.x, w = t >> 6, l = t & 63;
  const int q = l >> 4, ln = l & 15;
  const int r0 = blockIdx.x * 64;
  const int b = r0 >> 11;
  const int mloc = r0 & 2047;

  {  // stage WBT -> wt[f][k]
    const int f = t >> 2, c = t & 3;
    const unsigned short* src = WBT + f * 256;
    #pragma unroll
    for (int j = 0; j < 8; ++j) {
      const int k8 = c + j * 4;
      bf16x8 v = *(const bf16x8*)(src + k8 * 8);
      *(bf16x8*)(wt + ((f * 512 + k8 * 16) ^ ((f & 7) << 4))) = v;
    }
  }
  {  // stage h_B -> hl[row][k] (fp32 -> bf16)
    const int row = t >> 2, seg = t & 3;
    const float* src = hB + (size_t)(r0 + row) * 256 + seg * 64;
    #pragma unroll
    for (int i = 0; i < 8; ++i) {
      float4 x = *(const float4*)(src + i * 8);
      float4 y = *(const float4*)(src + i * 8 + 4);
      bf16x8 v;
      v[0] = (short)f2bf(x.x); v[1] = (short)f2bf(x.y);
      v[2] = (short)f2bf(x.z); v[3] = (short)f2bf(x.w);
      v[4] = (short)f2bf(y.x); v[5] = (short)f2bf(y.y);
      v[6] = (short)f2bf(y.z); v[7] = (short)f2bf(y.w);
      *(bf16x8*)(hl + ((row * 512 + seg * 128 + i * 16) ^ ((row & 7) << 4))) = v;
    }
  }
  __syncthreads();
  f32x4 acc[4];
  #pragma unroll
  for (int nr = 0; nr < 4; ++nr) acc[nr] = (f32x4){0.f, 0.f, 0.f, 0.f};
  const int rowA = w * 16 + ln;
  #pragma unroll
  for (int kk = 0; kk < 8; ++kk) {
    const int ko = kk * 64 + q * 16;
    bf16x8 a = *(const bf16x8*)(hl + ((rowA * 512 + ko) ^ ((rowA & 7) << 4)));
    #pragma unroll
    for (int nr = 0; nr < 4; ++nr) {
      const int f = nr * 16 + ln;
      bf16x8 bb = *(const bf16x8*)(wt + ((f * 512 + ko) ^ ((f & 7) << 4)));
      acc[nr] = __builtin_amdgcn_mfma_f32_16x16x32_bf16(a, bb, acc[nr], 0, 0, 0);
    }
  }
  // epilogue: bias, sB, block max, transpose-store via LDS
  float z[4][4];
  float p[4] = {0.f, 0.f, 0.f, 0.f};
  #pragma unroll
  for (int nr = 0; nr < 4; ++nr) {
    const int f = nr * 16 + ln;
    const float bias = WB_b[f];
    const float aw = aB_w[f];
    #pragma unroll
    for (int r = 0; r < 4; ++r) {
      const float zz = acc[nr][r] + bias;
      z[nr][r] = zz;
      p[r] += zz * aw;
    }
  }
  #pragma unroll
  for (int r = 0; r < 4; ++r) {
    #pragma unroll
    for (int off = 1; off < 16; off <<= 1) p[r] += __shfl_xor(p[r], off, 16);
  }
  if (ln == 0) {
    const float cb = aB_b[0];
    float lm = -1e30f;
    #pragma unroll
    for (int r = 0; r < 4; ++r) {
      const float s = p[r] + cb;
      sB[r0 + w * 16 + q * 4 + r] = s;
      lm = fmaxf(lm, s);
    }
    red16[w * 4 + q] = lm;
  }
  __syncthreads();  // hl reused as zt[f][m] bf16; red16 ready
  if (t == 0) {
    float bm = red16[0];
    #pragma unroll
    for (int i = 1; i < 16; ++i) bm = fmaxf(bm, red16[i]);
    msB_blk[blockIdx.x] = bm;
  }
  #pragma unroll
  for (int nr = 0; nr < 4; ++nr) {
    const int f = nr * 16 + ln;
    uint2 pk;
    pk.x = (unsigned)f2bf(z[nr][0]) | ((unsigned)f2bf(z[nr][1]) << 16);
    pk.y = (unsigned)f2bf(z[nr][2]) | ((unsigned)f2bf(z[nr][3]) << 16);
    *(uint2*)(hl + ((f * 128 + (w * 16 + q * 4) * 2) ^ ((f & 7) << 4))) = pk;
  }
  __syncthreads();
  {
    const int sf = t >> 3, sm8 = t & 7;
    #pragma unroll
    for (int i = 0; i < 2; ++i) {
      const int f = sf + i * 32;
      bf16x8 v = *(const bf16x8*)(hl + ((f * 128 + sm8 * 16) ^ ((f & 7) << 4)));
      *(bf16x8*)(zBT + (size_t)b * 131072 + f * 2048 + mloc + sm8 * 8) = v;
    }
  }
}

// Fused GAT: per (batch, 32-n tile): compute sA in-block, K-loop over m in
// tiles of 128, double-buffered LDS, one barrier per iteration.
__global__ __launch_bounds__(256) void gat_kernel(
    const unsigned short* __restrict__ zBT, const float* __restrict__ hA,
    const float* __restrict__ vA, const float* __restrict__ cA,
    const float* __restrict__ sB, const float* __restrict__ msB_blk,
    const unsigned char* __restrict__ mask8, const int* __restrict__ mask32,
    const int* __restrict__ mflag, float* __restrict__ out) {
  const int b = blockIdx.y;
  const int n0 = blockIdx.x * 32;
  const int t = threadIdx.x;
  const int w = t >> 6, l = t & 63;
  const int q = l >> 4, ln = l & 15;
  const bool use8 = (*mflag != 0);

  __shared__ char zbl[2][16384];  // [64 f][128 m] bf16, 256B rows, XOR-swizzled
  __shared__ char wl[2][8192];    // [32 n][128 m] bf16, 256B rows, XOR-swizzled
  __shared__ float sAl[32];
  __shared__ float dl[32];

  // phase 0: sA for this block's 32 rows (one row per wave-step, float4/lane)
  const float4 vA4 = ((const float4*)vA)[l];
  const float cA0 = cA[0];
  #pragma unroll
  for (int r = 0; r < 8; ++r) {
    const int row = w * 8 + r;
    const float4 h4 = *(const float4*)(hA + ((size_t)(b * 2048 + n0 + row)) * 256 + l * 4);
    float s = h4.x * vA4.x + h4.y * vA4.y + h4.z * vA4.z + h4.w * vA4.w;
    s = wave_reduce_sum(s);
    if (l == 0) sAl[row] = s + cA0;
  }
  float mb = -1e30f;
  #pragma unroll 8
  for (int i = 0; i < 32; ++i) mb = fmaxf(mb, msB_blk[b * 32 + i]);
  __syncthreads();

  const int n2 = t >> 4;   // rows n2, n2+16
  const int m8 = t & 15;   // 8 m's per row per thread
  const float sA0 = sAl[n2], sA1 = sAl[n2 + 16];
  const float M0f = sA0 + mb, M1f = sA1 + mb;
  const float M0 = M0f >= 0.f ? M0f : 0.01f * M0f;
  const float M1 = M1f >= 0.f ? M1f : 0.01f * M1f;
  float ds0 = 0.f, ds1 = 0.f;
  f32x4 acc0 = (f32x4){0.f, 0.f, 0.f, 0.f}, acc1 = acc0;

  const unsigned short* zb = zBT + (size_t)b * 131072;
  const size_t mrow0 = ((size_t)(b * 2048 + n0 + n2)) * 2048 + m8 * 8;
  const size_t mrow1 = mrow0 + (size_t)16 * 2048;
  const int zf = t >> 2, zseg = t & 3;  // staging: row zf, 64B segment zseg
  const int fB = w * 16 + ln;
  const int wbyte0 = (n2 * 256 + m8 * 16) ^ ((n2 & 7) << 4);
  const int wbyte1 = ((n2 + 16) * 256 + m8 * 16) ^ (((n2 + 16) & 7) << 4);

  for (int mt = 0; mt < 16; ++mt) {
    const int m0 = mt * 128;
    char* zc = zbl[mt & 1];
    char* wc = wl[mt & 1];
    // issue global loads early
    bf16x8 zv[4];
    #pragma unroll
    for (int i = 0; i < 4; ++i)
      zv[i] = *(const bf16x8*)(zb + zf * 2048 + m0 + zseg * 32 + i * 8);
    const float4 s0 = *(const float4*)(sB + b * 2048 + m0 + m8 * 8);
    const float4 s1 = *(const float4*)(sB + b * 2048 + m0 + m8 * 8 + 4);
    const float sbx[8] = {s0.x, s0.y, s0.z, s0.w, s1.x, s1.y, s1.z, s1.w};
    int k0[8], k1[8];
    if (use8) {
      const uint2 a = *(const uint2*)(mask8 + mrow0 + m0);
      const uint2 c = *(const uint2*)(mask8 + mrow1 + m0);
      #pragma unroll
      for (int j = 0; j < 4; ++j) {
        k0[j] = (a.x >> (8 * j)) & 0xFF; k0[j + 4] = (a.y >> (8 * j)) & 0xFF;
        k1[j] = (c.x >> (8 * j)) & 0xFF; k1[j + 4] = (c.y >> (8 * j)) & 0xFF;
      }
    } else {
      const int4 a = *(const int4*)(mask32 + mrow0 + m0);
      const int4 a2 = *(const int4*)(mask32 + mrow0 + m0 + 4);
      const int4 c = *(const int4*)(mask32 + mrow1 + m0);
      const int4 c2 = *(const int4*)(mask32 + mrow1 + m0 + 4);
      k0[0] = a.x; k0[1] = a.y; k0[2] = a.z; k0[3] = a.w;
      k0[4] = a2.x; k0[5] = a2.y; k0[6] = a2.z; k0[7] = a2.w;
      k1[0] = c.x; k1[1] = c.y; k1[2] = c.z; k1[3] = c.w;
      k1[4] = c2.x; k1[5] = c2.y; k1[6] = c2.z; k1[7] = c2.w;
    }
    unsigned short wb0[8], wb1[8];
    #pragma unroll
    for (int j = 0; j < 8; ++j) {
      const float x0 = sA0 + sbx[j];
      const float e0 = x0 >= 0.f ? x0 : 0.01f * x0;
      const float v0 = k0[j] ? __expf(e0 - M0) : 0.f;
      wb0[j] = f2bf(v0); ds0 += bf2f(wb0[j]);
      const float x1 = sA1 + sbx[j];
      const float e1 = x1 >= 0.f ? x1 : 0.01f * x1;
      const float v1 = k1[j] ? __expf(e1 - M1) : 0.f;
      wb1[j] = f2bf(v1); ds1 += bf2f(wb1[j]);
    }
    // LDS writes
    #pragma unroll
    for (int i = 0; i < 4; ++i)
      *(bf16x8*)(zc + ((zf * 256 + zseg * 64 + i * 16) ^ ((zf & 7) << 4))) = zv[i];
    uint4 pk0, pk1;
    pk0.x = (unsigned)wb0[0] | ((unsigned)wb0[1] << 16);
    pk0.y = (unsigned)wb0[2] | ((unsigned)wb0[3] << 16);
    pk0.z = (unsigned)wb0[4] | ((unsigned)wb0[5] << 16);
    pk0.w = (unsigned)wb0[6] | ((unsigned)wb0[7] << 16);
    pk1.x = (unsigned)wb1[0] | ((unsigned)wb1[1] << 16);
    pk1.y = (unsigned)wb1[2] | ((unsigned)wb1[3] << 16);
    pk1.z = (unsigned)wb1[4] | ((unsigned)wb1[5] << 16);
    pk1.w = (unsigned)wb1[6] | ((unsigned)wb1[7] << 16);
    *(uint4*)(wc + wbyte0) = pk0;
    *(uint4*)(wc + wbyte1) = pk1;
    __syncthreads();
    #pragma unroll
    for (int kk = 0; kk < 4; ++kk) {
      const int ko = kk * 64 + q * 16;
      bf16x8 bb = *(const bf16x8*)(zc + ((fB * 256 + ko) ^ ((fB & 7) << 4)));
      bf16x8 a0 = *(const bf16x8*)(wc + ((ln * 256 + ko) ^ ((ln & 7) << 4)));
      bf16x8 a1 = *(const bf16x8*)(wc + (((16 + ln) * 256 + ko) ^ (((16 + ln) & 7) << 4)));
      acc0 = __builtin_amdgcn_mfma_f32_16x16x32_bf16(a0, bb, acc0, 0, 0, 0);
      acc1 = __builtin_amdgcn_mfma_f32_16x16x32_bf16(a1, bb, acc1, 0, 0, 0);
    }
  }
  #pragma unroll
  for (int off = 1; off < 16; off <<= 1) {
    ds0 += __shfl_xor(ds0, off, 16);
    ds1 += __shfl_xor(ds1, off, 16);
  }
  if (m8 == 0) { dl[n2] = ds0; dl[n2 + 16] = ds1; }
  __syncthreads();
  #pragma unroll
  for (int r = 0; r < 4; ++r) {
    {
      const int n = q * 4 + r;
      const float d = dl[n];
      out[((size_t)(b * 2048 + n0 + n)) * 64 + w * 16 + ln] = d > 0.f ? acc0[r] / d : 0.f;
    }
    {
      const int n = 16 + q * 4 + r;
      const float d = dl[n];
      out[((size_t)(b * 2048 + n0 + n)) * 64 + w * 16 + ln] = d > 0.f ? acc1[r] / d : 0.f;
    }
  }
}

extern "C" void kernel_launch(void* const* d_in, const int* in_sizes, int n_in,
                              void* d_out, int out_size, void* d_ws, size_t ws_size,
                              hipStream_t stream) {
  const float* h_A = (const float*)d_in[0];
  const float* h_B = (const float*)d_in[1];
  const unsigned char* mask8 = (const unsigned char*)d_in[2];
  const int* mask32 = (const int*)d_in[2];
  const float* WA_w = (const float*)d_in[3];
  const float* WA_b = (const float*)d_in[4];
  const float* WB_w = (const float*)d_in[5];
  const float* WB_b = (const float*)d_in[6];
  const float* aA_w = (const float*)d_in[7];
  const float* aA_b = (const float*)d_in[8];
  const float* aB_w = (const float*)d_in[9];
  const float* aB_b = (const float*)d_in[10];
  float* out = (float*)d_out;

  char* wsb = (char*)d_ws;
  unsigned short* zBT = (unsigned short*)wsb;              // 2,097,152 B
  unsigned short* WBT = (unsigned short*)(wsb + 2097152);  // 32,768 B
  float* sB      = (float*)(wsb + 2129920);                // 65,536 B
  float* vA      = (float*)(wsb + 2195456);                // 1,024 B
  float* cA      = (float*)(wsb + 2196480);                // 4 B
  float* msB_blk = (float*)(wsb + 2196484);                // 1,024 B
  int* mflag     = (int*)(wsb + 2197508);                  // 4 B

  prep_kernel<<<65, 256, 0, stream>>>(WA_w, WA_b, aA_w, aA_b, WB_w, mask8,
                                      vA, cA, WBT, mflag);
  zB_kernel<<<256, 256, 0, stream>>>(h_B, WBT, WB_b, aB_w, aB_b, zBT, sB, msB_blk);
  gat_kernel<<<dim3(64, 8), 256, 0, stream>>>(zBT, h_A, vA, cA, sB, msB_blk,
                                              mask8, mask32, mflag, out);
}

// Round 6
// 59.305 us; speedup vs baseline: 5.3306x; 1.0784x over previous
//
#include <hip/hip_runtime.h>

// B=8, NA=NB=2048, in=256, D=64
typedef short bf16x8 __attribute__((ext_vector_type(8)));
typedef float f32x4 __attribute__((ext_vector_type(4)));

__device__ __forceinline__ unsigned short f2bf(float x) {
  unsigned u = __float_as_uint(x);
  u += 0x7FFFu + ((u >> 16) & 1u);
  return (unsigned short)(u >> 16);
}
__device__ __forceinline__ float bf2f(unsigned short h) {
  return __uint_as_float(((unsigned)h) << 16);
}

// ============ zB: z_B^T (bf16) + sB + per-block max(sB) ============
// 512 blocks x 32 m-rows. Inline W transpose (no prep kernel).
__global__ __launch_bounds__(256) void zb_kernel(
    const float* __restrict__ hB, const float* __restrict__ WB_w,
    const float* __restrict__ WB_b, const float* __restrict__ aB_w,
    const float* __restrict__ aB_b,
    unsigned short* __restrict__ zBT, float* __restrict__ sB,
    float* __restrict__ msB_blk) {
  __shared__ char wt[32768];   // [64 f][256 k] bf16, 512B rows, XOR swizzle
  __shared__ char hl[16384];   // [32 m][256 k] bf16, 512B rows; reused as zt
  __shared__ float redp[4][16];
  __shared__ float sred[32];

  const int t = threadIdx.x, w = t >> 6, l = t & 63;
  const int q = l >> 4, ln = l & 15;
  const int m0g = blockIdx.x * 32;
  const int b = m0g >> 11, mloc = m0g & 2047;

  {  // stage wt[f][k] = bf16(WB_w[k][f])
    const int f = t >> 2, kseg = t & 3;
    #pragma unroll
    for (int j = 0; j < 8; ++j) {
      const int k0 = kseg * 64 + j * 8;
      bf16x8 v;
      #pragma unroll
      for (int jj = 0; jj < 8; ++jj)
        v[jj] = (short)f2bf(WB_w[(k0 + jj) * 64 + f]);
      *(bf16x8*)(wt + ((f * 512 + k0 * 2) ^ ((f & 7) << 4))) = v;
    }
  }
  {  // stage hl[row][k] = bf16(hB[m0g+row][k]), coalesced float4
    #pragma unroll
    for (int i = 0; i < 8; ++i) {
      const int idx = i * 1024 + t * 4;
      const int row = idx >> 8, k = idx & 255;
      const float4 x = *(const float4*)(hB + (size_t)m0g * 256 + idx);
      uint2 pk;
      pk.x = (unsigned)f2bf(x.x) | ((unsigned)f2bf(x.y) << 16);
      pk.y = (unsigned)f2bf(x.z) | ((unsigned)f2bf(x.w) << 16);
      *(uint2*)(hl + ((row * 512 + k * 2) ^ ((row & 7) << 4))) = pk;
    }
  }
  __syncthreads();
  const int rt = w & 1, fpair = w >> 1;
  f32x4 acc[2];
  acc[0] = (f32x4){0.f, 0.f, 0.f, 0.f};
  acc[1] = acc[0];
  const int rowA = rt * 16 + ln;
  #pragma unroll
  for (int kk = 0; kk < 8; ++kk) {
    const int ko = kk * 64 + q * 16;
    const bf16x8 a = *(const bf16x8*)(hl + ((rowA * 512 + ko) ^ ((rowA & 7) << 4)));
    #pragma unroll
    for (int j = 0; j < 2; ++j) {
      const int f = fpair * 32 + j * 16 + ln;
      const bf16x8 bb = *(const bf16x8*)(wt + ((f * 512 + ko) ^ ((f & 7) << 4)));
      acc[j] = __builtin_amdgcn_mfma_f32_16x16x32_bf16(a, bb, acc[j], 0, 0, 0);
    }
  }
  float z[2][4];
  float p[4] = {0.f, 0.f, 0.f, 0.f};
  #pragma unroll
  for (int j = 0; j < 2; ++j) {
    const int f = fpair * 32 + j * 16 + ln;
    const float bias = WB_b[f], aw = aB_w[f];
    #pragma unroll
    for (int r = 0; r < 4; ++r) {
      const float zz = acc[j][r] + bias;
      z[j][r] = zz;
      p[r] += zz * aw;
    }
  }
  #pragma unroll
  for (int r = 0; r < 4; ++r) {
    #pragma unroll
    for (int off = 1; off < 16; off <<= 1) p[r] += __shfl_xor(p[r], off, 16);
  }
  if (ln == 0) {
    #pragma unroll
    for (int r = 0; r < 4; ++r) redp[w][q * 4 + r] = p[r];
  }
  __syncthreads();  // hl free for reuse; redp ready
  char* zt = hl;    // [64 f][80 B] rows (32 m x 2B + 16B pad, bank-spread)
  #pragma unroll
  for (int j = 0; j < 2; ++j) {
    const int f = fpair * 32 + j * 16 + ln;
    uint2 pk;
    pk.x = (unsigned)f2bf(z[j][0]) | ((unsigned)f2bf(z[j][1]) << 16);
    pk.y = (unsigned)f2bf(z[j][2]) | ((unsigned)f2bf(z[j][3]) << 16);
    *(uint2*)(zt + f * 80 + (rt * 16 + q * 4) * 2) = pk;
  }
  if (t < 32) {  // rows rt: waves rt and rt+2 hold the two f-halves
    const int rtm = t >> 4, mi = t & 15;
    const float s = redp[rtm][mi] + redp[rtm + 2][mi] + aB_b[0];
    sB[m0g + t] = s;
    sred[t] = s;
  }
  __syncthreads();
  if (t == 0) {
    float bm = sred[0];
    #pragma unroll
    for (int i = 1; i < 32; ++i) bm = fmaxf(bm, sred[i]);
    msB_blk[blockIdx.x] = bm;
  }
  {
    const int f = t >> 2, mseg = t & 3;
    const bf16x8 v = *(const bf16x8*)(zt + f * 80 + mseg * 16);
    *(bf16x8*)(zBT + (size_t)b * 131072 + f * 2048 + mloc + mseg * 8) = v;
  }
}

// ============ gat: fused scores+softmax+PV ============
struct Pref {
  bf16x8 za, zb2;
  uint2 mk;
  int4 m32a, m32b;
};

__device__ __forceinline__ void gat_load(Pref& p,
    const unsigned short* zrow, const unsigned char* mk8, const int* mk32,
    const bool use8, const int m0) {
  p.za = *(const bf16x8*)(zrow + m0);
  p.zb2 = *(const bf16x8*)(zrow + m0 + 8);
  if (use8) {
    p.mk = *(const uint2*)(mk8 + m0);
  } else {
    p.m32a = *(const int4*)(mk32 + m0);
    p.m32b = *(const int4*)(mk32 + m0 + 4);
  }
}

__device__ __forceinline__ void gat_body(const Pref& p, char* zc, char* wc,
    const float* sBl, const int m0, const int m8, const float sAr, const float M,
    const bool use8, const int zw0, const int zw1, const int wbyte, float& ds) {
  *(bf16x8*)(zc + zw0) = p.za;
  *(bf16x8*)(zc + zw1) = p.zb2;
  const int sbase = m0 + m8 * 8;
  const float4 s0 = *(const float4*)(sBl + sbase);
  const float4 s1 = *(const float4*)(sBl + sbase + 4);
  const float sbx[8] = {s0.x, s0.y, s0.z, s0.w, s1.x, s1.y, s1.z, s1.w};
  int km[8];
  if (use8) {
    #pragma unroll
    for (int j = 0; j < 4; ++j) {
      km[j] = (p.mk.x >> (8 * j)) & 0xFF;
      km[j + 4] = (p.mk.y >> (8 * j)) & 0xFF;
    }
  } else {
    km[0] = p.m32a.x; km[1] = p.m32a.y; km[2] = p.m32a.z; km[3] = p.m32a.w;
    km[4] = p.m32b.x; km[5] = p.m32b.y; km[6] = p.m32b.z; km[7] = p.m32b.w;
  }
  unsigned short wb[8];
  #pragma unroll
  for (int j = 0; j < 8; ++j) {
    const float x = sAr + sbx[j];
    const float e = x >= 0.f ? x : 0.01f * x;
    const float v = km[j] ? __expf(e - M) : 0.f;
    wb[j] = f2bf(v);
    ds += bf2f(wb[j]);
  }
  uint4 pk;
  pk.x = (unsigned)wb[0] | ((unsigned)wb[1] << 16);
  pk.y = (unsigned)wb[2] | ((unsigned)wb[3] << 16);
  pk.z = (unsigned)wb[4] | ((unsigned)wb[5] << 16);
  pk.w = (unsigned)wb[6] | ((unsigned)wb[7] << 16);
  *(uint4*)(wc + wbyte) = pk;
}

__device__ __forceinline__ void gat_mfma(const char* zc, const char* wc,
    f32x4& acc, const int fb, const int ar, const int q) {
  #pragma unroll
  for (int kk = 0; kk < 4; ++kk) {
    const int ko = kk * 64 + q * 16;
    const bf16x8 bb = *(const bf16x8*)(zc + ((fb * 256 + ko) ^ ((fb & 7) << 4)));
    const bf16x8 aa = *(const bf16x8*)(wc + ((ar * 256 + ko) ^ ((ar & 7) << 4)));
    acc = __builtin_amdgcn_mfma_f32_16x16x32_bf16(aa, bb, acc, 0, 0, 0);
  }
}

__global__ __launch_bounds__(512, 4) void gat_kernel(
    const unsigned short* __restrict__ zBT, const float* __restrict__ hA,
    const float* __restrict__ WA_w, const float* __restrict__ WA_b,
    const float* __restrict__ aA_w, const float* __restrict__ aA_b,
    const float* __restrict__ sB, const float* __restrict__ msB_blk,
    const unsigned char* __restrict__ mask8, const int* __restrict__ mask32,
    float* __restrict__ out) {
  const int b = blockIdx.y, n0 = blockIdx.x * 32;
  const int t = threadIdx.x, w = t >> 6, l = t & 63;
  const int q = l >> 4, ln = l & 15;

  __shared__ char zbl0[16384], zbl1[16384];  // [64 f][128 m] bf16 swizzled
  __shared__ char wl0[8192], wl1[8192];      // [32 n][128 m] bf16 swizzled
  __shared__ float sBl[2048];
  __shared__ float vAl[256];
  __shared__ float sAl[32];
  __shared__ float dl[32];
  __shared__ float cAl;
  __shared__ unsigned dfl[4];

  // ---- phase 0: detect, vA, cA, sB preload, msB, sA ----
  if (t < 256) {
    const unsigned vdet = mask8[t * 4 + 1];  // 0 for int32/fp32 0/1; random for bool
    const unsigned long long bal = __ballot(vdet != 0);
    if (l == 0) dfl[w] = (bal != 0ull) ? 1u : 0u;
    const float4* wr = (const float4*)(WA_w + t * 64);
    const float4* a4 = (const float4*)aA_w;
    float s = 0.f;
    #pragma unroll
    for (int i = 0; i < 16; ++i) {
      const float4 x = wr[i], y = a4[i];
      s += x.x * y.x + x.y * y.y + x.z * y.z + x.w * y.w;
    }
    vAl[t] = s;
  } else {
    const int u = t - 256;
    ((float4*)sBl)[u * 2] = ((const float4*)(sB + b * 2048))[u * 2];
    ((float4*)sBl)[u * 2 + 1] = ((const float4*)(sB + b * 2048))[u * 2 + 1];
    if (u == 0) {
      float ca = aA_b[0];
      for (int f = 0; f < 64; ++f) ca += WA_b[f] * aA_w[f];
      cAl = ca;
    }
  }
  float mb = msB_blk[b * 64 + l];
  #pragma unroll
  for (int off = 1; off < 64; off <<= 1) mb = fmaxf(mb, __shfl_xor(mb, off, 64));
  __syncthreads();
  const bool use8 = (dfl[0] | dfl[1] | dfl[2] | dfl[3]) != 0;
  {
    const float4 vA4 = ((const float4*)vAl)[l];
    const float cA0 = cAl;
    #pragma unroll
    for (int rr = 0; rr < 4; ++rr) {
      const int row = w * 4 + rr;
      const float4 h4 = *(const float4*)(hA + ((size_t)(b * 2048 + n0 + row)) * 256 + l * 4);
      float s = h4.x * vA4.x + h4.y * vA4.y + h4.z * vA4.z + h4.w * vA4.w;
      #pragma unroll
      for (int off = 1; off < 64; off <<= 1) s += __shfl_xor(s, off, 64);
      if (l == 0) sAl[row] = s + cA0;
    }
  }
  __syncthreads();

  // ---- main loop: 16 m-tiles of 128, double-buffered, 1-tile reg prefetch ----
  const int r = t >> 4, m8 = t & 15;
  const float sAr = sAl[r];
  const float Mf = sAr + mb;
  const float M = Mf >= 0.f ? Mf : 0.01f * Mf;  // leaky is monotone: safe upper bound
  float ds = 0.f;
  f32x4 acc = (f32x4){0.f, 0.f, 0.f, 0.f};

  const int zf = t >> 3, zseg = t & 7;
  const unsigned short* zrow = zBT + (size_t)b * 131072 + zf * 2048 + zseg * 16;
  const size_t mrowe = ((size_t)(b * 2048 + n0 + r)) * 2048 + m8 * 8;
  const unsigned char* mk8 = mask8 + mrowe;
  const int* mk32 = mask32 + mrowe;
  const int zbase = zf * 256 + zseg * 32;
  const int swz = (zf & 7) << 4;
  const int zw0 = zbase ^ swz, zw1 = (zbase + 16) ^ swz;
  const int wbyte = (r * 256 + m8 * 16) ^ ((r & 7) << 4);
  const int fb = (w >> 1) * 16 + ln;
  const int ar = (w & 1) * 16 + ln;

  Pref pA, pB;
  gat_load(pA, zrow, mk8, mk32, use8, 0);
  for (int mt = 0; mt < 16; mt += 2) {
    gat_load(pB, zrow, mk8, mk32, use8, (mt + 1) * 128);
    gat_body(pA, zbl0, wl0, sBl, mt * 128, m8, sAr, M, use8, zw0, zw1, wbyte, ds);
    __syncthreads();
    gat_mfma(zbl0, wl0, acc, fb, ar, q);
    gat_load(pA, zrow, mk8, mk32, use8, ((mt + 2) & 15) * 128);
    gat_body(pB, zbl1, wl1, sBl, (mt + 1) * 128, m8, sAr, M, use8, zw0, zw1, wbyte, ds);
    __syncthreads();
    gat_mfma(zbl1, wl1, acc, fb, ar, q);
  }
  #pragma unroll
  for (int off = 1; off < 16; off <<= 1) ds += __shfl_xor(ds, off, 16);
  if (m8 == 0) dl[r] = ds;
  __syncthreads();
  #pragma unroll
  for (int rr = 0; rr < 4; ++rr) {
    const int n = (w & 1) * 16 + q * 4 + rr;
    const float d = dl[n];
    out[((size_t)(b * 2048 + n0 + n)) * 64 + fb] = d > 0.f ? acc[rr] / d : 0.f;
  }
}

extern "C" void kernel_launch(void* const* d_in, const int* in_sizes, int n_in,
                              void* d_out, int out_size, void* d_ws, size_t ws_size,
                              hipStream_t stream) {
  const float* h_A = (const float*)d_in[0];
  const float* h_B = (const float*)d_in[1];
  const unsigned char* mask8 = (const unsigned char*)d_in[2];
  const int* mask32 = (const int*)d_in[2];
  const float* WA_w = (const float*)d_in[3];
  const float* WA_b = (const float*)d_in[4];
  const float* WB_w = (const float*)d_in[5];
  const float* WB_b = (const float*)d_in[6];
  const float* aA_w = (const float*)d_in[7];
  const float* aA_b = (const float*)d_in[8];
  const float* aB_w = (const float*)d_in[9];
  const float* aB_b = (const float*)d_in[10];
  float* out = (float*)d_out;

  char* wsb = (char*)d_ws;
  unsigned short* zBT = (unsigned short*)wsb;        // 2,097,152 B
  float* sB      = (float*)(wsb + 2097152);          // 65,536 B
  float* msB_blk = (float*)(wsb + 2162688);          // 2,048 B

  zb_kernel<<<512, 256, 0, stream>>>(h_B, WB_w, WB_b, aB_w, aB_b, zBT, sB, msB_blk);
  gat_kernel<<<dim3(64, 8), 512, 0, stream>>>(zBT, h_A, WA_w, WA_b, aA_w, aA_b,
                                              sB, msB_blk, mask8, mask32, out);
}